// Round 14
// baseline (445.297 us; speedup 1.0000x reference)
//
#include <hip/hip_runtime.h>

#define NN 32768
#define NE 524288
#define HD 256
#define TOTP 794897

#define GAS __attribute__((address_space(1)))
#define LAS __attribute__((address_space(3)))

typedef __attribute__((ext_vector_type(8))) __bf16 bf16x8;
typedef __attribute__((ext_vector_type(4))) float f32x4;

__device__ __forceinline__ float ld_any(const void* p, int i, int isbf16) {
    return isbf16 ? (float)((const __bf16*)p)[i] : ((const float*)p)[i];
}

struct PtrTable { const void* p[18]; };

// ---------------- fused preprocessing: detect + cvt_params + cvt_x0 + deg ----------------

__global__ __launch_bounds__(256) void k_pre(const unsigned* __restrict__ xw, const int* __restrict__ ei,
                                             PtrTable pt, const void* __restrict__ p0, const void* __restrict__ p1,
                                             const void* __restrict__ p2, const void* __restrict__ p3,
                                             int* __restrict__ flags, int* __restrict__ deg,
                                             __bf16* __restrict__ blob, __bf16* __restrict__ X0c) {
    __shared__ int fl[2];
    const int t = threadIdx.x;
    if (t < 64) {
        unsigned L = xw[t] & 0xFFFFu;
        int e = (int)((L >> 7) & 0xFF);
        unsigned long long b = __ballot(e >= 90 && e <= 135);
        if (t == 0) fl[0] = (b == ~0ULL) ? 1 : 0;  // 1 => bf16 inputs
    } else if (t < 128) {
        int u = t - 64;
        unsigned long long b = __ballot(ei[2 * u + 1] != 0);
        if (t == 64) fl[1] = (b == 0ULL) ? 1 : 0;  // 1 => int64 edges
    }
    __syncthreads();
    const int f0 = fl[0], f1 = fl[1];
    const int blk = blockIdx.x;
    if (blk == 0 && t < 2) flags[t] = fl[t];
    if (blk < 2048) {
        int i0 = (blk * 256 + t) * 8;
        int n = i0 >> 7, f = i0 & 127;
        const void* src = (f < 32) ? p0 : (f < 64) ? p1 : (f < 96) ? p2 : p3;
        int si = n * 32 + (f & 31);
        bf16x8 o;
        #pragma unroll
        for (int j = 0; j < 8; ++j) o[j] = (__bf16)ld_any(src, si + j, f0);
        *(bf16x8*)&X0c[i0] = o;
    } else if (blk < 3601) {
        const int off[23] = {0, 32768, 65536, 65792, 131328, 196864, 262400, 327936, 393472,
                             459008, 459776, 460800, 461824, 723968, 724224, 724480, 724481,
                             724737, 724993, 790529, 790785, 794881, TOTP};
        const signed char pidx[22] = {0, 1, 2, 3, 3, 3, 4, 4, 4, 5, 6, 7, 8, 9, 10, 11, 12, 13, 14, 15, 16, 17};
        const int sbase[22] = {0, 0, 0, 0, 65536, 131072, 0, 65536, 131072, 0, 0, 0, 0, 0, 0, 0, 0, 0, 0, 0, 0, 0};
        const signed char lR[22] = {7, 7, -1, 8, 8, 8, 8, 8, 8, -1, -1, -1, 10, -1, -1, -1, -1, -1, -1, -1, -1, -1};
        const signed char lC[22] = {8, 8, 0, 8, 8, 8, 8, 8, 8, 0, 0, 0, 8, 0, 0, 0, 0, 0, 0, 0, 0, 0};
        int base = ((blk - 2048) * 256 + t) * 2;
        #pragma unroll
        for (int j = 0; j < 2; ++j) {
            int i = base + j;
            if (i >= TOTP) break;
            int s = 0;
            while (i >= off[s + 1]) ++s;
            int jj = i - off[s];
            int si;
            if (lR[s] >= 0) {
                int Rm = (1 << lR[s]) - 1;
                si = sbase[s] + ((jj & Rm) << lC[s]) + (jj >> lR[s]);  // transpose read
            } else {
                si = sbase[s] + jj;
            }
            blob[i] = (__bf16)ld_any(pt.p[pidx[s]], si, f0);
        }
    } else {
        int e0 = ((blk - 3601) * 256 + t) * 2;
        int d0 = f1 ? ei[2 * e0] : ei[e0];
        int d1 = f1 ? ei[2 * e0 + 2] : ei[e0 + 1];
        atomicAdd(&deg[d0], 1);
        atomicAdd(&deg[d1], 1);
    }
}

// ---------------- CSR region allocation ----------------

__global__ __launch_bounds__(256) void k_alloc(const int* __restrict__ deg, int* __restrict__ gcur,
                                               int* __restrict__ offs, float* __restrict__ invd) {
    const int n = blockIdx.x * 256 + threadIdx.x;
    const int lane = threadIdx.x & 63;
    const int v = deg[n];
    invd[n] = v ? 1.f / (float)v : 0.f;
    int incl = v;
    #pragma unroll
    for (int d = 1; d < 64; d <<= 1) {
        int y = __shfl_up(incl, d, 64);
        if (lane >= d) incl += y;
    }
    int base = 0;
    if (lane == 63) base = atomicAdd(gcur, incl);
    base = __shfl(base, 63, 64);
    offs[n] = base + incl - v;
}

__global__ __launch_bounds__(256) void k_fill(const int* __restrict__ ei, const int* __restrict__ flags,
                                              const int* __restrict__ offs, int* __restrict__ cursor,
                                              int* __restrict__ csr) {
    int e = blockIdx.x * 256 + threadIdx.x;
    int f = flags[1];
    int d = f ? ei[2 * e] : ei[e];
    int s = f ? ei[2 * NE + 2 * e] : ei[NE + e];
    int p = atomicAdd(&cursor[d], 1);
    csr[offs[d] + p] = s;
}

// ---------------- mean aggregation, slice statically bound to XCD ----------------
// blockIdx % nslices = slice; each XCD's 4 MB L2 holds one 64-feat column slice
// (FETCH 105 -> 37 MB, r10). csr/X loads CACHED (NT on csr cost +20us/agg, r10).
// 16-wide fully-unrolled MASKED edge blocks: 16 independent 128B gathers in
// flight per lane (r12's 8-wide was 13.4 TB/s agg L2 = 40% of ceiling, still
// latency-bound). Masked slots clamp to csr[end-1] (hot line, L1-served).
// Sequential e-order per feature preserved => bit-identical sums.

__global__ __launch_bounds__(256) void k_agg0(const __bf16* __restrict__ X, const int* __restrict__ csr,
                                              const int* __restrict__ offs, const int* __restrict__ deg,
                                              const float* __restrict__ invd, __bf16* __restrict__ M) {
    const int t = threadIdx.x;
    const int s = blockIdx.x & 1;           // slice (2 x 64 feats, 4 MB each)
    const int n = (blockIdx.x >> 1) * 32 + (t >> 3);
    const int fo = s * 64 + (t & 7) * 8;
    const int beg = offs[n], end = beg + deg[n];
    float a[8] = {};
    for (int e = beg; e < end; e += 16) {
        #pragma unroll
        for (int u = 0; u < 16; ++u) {
            int ee = e + u;
            int idx = csr[ee < end ? ee : end - 1] & (NN - 1);
            float mk = ee < end ? 1.f : 0.f;
            bf16x8 v = *(const bf16x8*)&X[(size_t)idx * 128 + fo];
            #pragma unroll
            for (int j = 0; j < 8; ++j) a[j] += mk * (float)v[j];
        }
    }
    const float id = invd[n];
    bf16x8 o;
    #pragma unroll
    for (int j = 0; j < 8; ++j) o[j] = (__bf16)(a[j] * id);
    *(bf16x8*)&M[(size_t)n * 128 + fo] = o;
}

__global__ __launch_bounds__(256) void k_agg(const __bf16* __restrict__ X, const int* __restrict__ csr,
                                             const int* __restrict__ offs, const int* __restrict__ deg,
                                             const float* __restrict__ invd, __bf16* __restrict__ M) {
    const int t = threadIdx.x;
    const int s = blockIdx.x & 3;           // slice (4 x 64 feats, 4 MB each)
    const int n = (blockIdx.x >> 2) * 32 + (t >> 3);
    const int fo = s * 64 + (t & 7) * 8;
    const int beg = offs[n], end = beg + deg[n];
    float a[8] = {};
    for (int e = beg; e < end; e += 16) {
        #pragma unroll
        for (int u = 0; u < 16; ++u) {
            int ee = e + u;
            int idx = csr[ee < end ? ee : end - 1] & (NN - 1);
            float mk = ee < end ? 1.f : 0.f;
            bf16x8 v = *(const bf16x8*)&X[(size_t)idx * HD + fo];
            #pragma unroll
            for (int j = 0; j < 8; ++j) a[j] += mk * (float)v[j];
        }
    }
    const float id = invd[n];
    bf16x8 o;
    #pragma unroll
    for (int j = 0; j < 8; ++j) o[j] = (__bf16)(a[j] * id);
    *(bf16x8*)&M[(size_t)n * HD + fo] = o;
}

// ---------------- MFMA GEMM, BK=64 ----------------

template <int MODE, int TM>
__global__ __launch_bounds__(256) void k_gemm(const __bf16* __restrict__ A1, const __bf16* __restrict__ WT1,
                                              const __bf16* __restrict__ A2, const __bf16* __restrict__ WT2,
                                              const __bf16* __restrict__ bias, int KD,
                                              __bf16* __restrict__ O, float* __restrict__ colsum,
                                              const __bf16* __restrict__ W1b, float* __restrict__ x2) {
    constexpr int MI = TM / 32;
    __shared__ __bf16 As[2][TM][32];
    __shared__ __bf16 Bs[2][128][32];
    const int t = threadIdx.x;
    const int lane = t & 63, w = t >> 6;
    const int wm = w >> 1, wn = w & 1;
    const int quad = lane >> 4, l15 = lane & 15;
    const int row0 = blockIdx.x * TM, c0 = blockIdx.y * 128;
    const int dr = lane >> 2, dc = (lane & 3) * 8;
    f32x4 acc[MI][4] = {};
    const int npass = A2 ? 2 : 1;
    for (int pass = 0; pass < npass; ++pass) {
        const __bf16* __restrict__ A = pass ? A2 : A1;
        const __bf16* __restrict__ WT = pass ? WT2 : WT1;
        for (int k0 = 0; k0 < KD; k0 += 64) {
            __syncthreads();
            #pragma unroll
            for (int kk = 0; kk < 2; ++kk) {
                #pragma unroll
                for (int i = 0; i < 2; ++i) {
                    const __bf16* g = &WT[(size_t)(c0 + w * 32 + i * 16 + dr) * KD + k0 + kk * 32 + dc];
                    __builtin_amdgcn_global_load_lds((const GAS void*)g, (LAS void*)&Bs[kk][w * 32 + i * 16][0],
                                                     16, 0, 0);
                }
                #pragma unroll
                for (int i = 0; i < TM / 64; ++i) {
                    const __bf16* g = &A[(size_t)(row0 + w * (TM / 4) + i * 16 + dr) * KD + k0 + kk * 32 + dc];
                    __builtin_amdgcn_global_load_lds((const GAS void*)g,
                                                     (LAS void*)&As[kk][w * (TM / 4) + i * 16][0], 16, 0, 0);
                }
            }
            __syncthreads();
            #pragma unroll
            for (int kk = 0; kk < 2; ++kk) {
                bf16x8 af[MI], bfr[4];
                #pragma unroll
                for (int i = 0; i < MI; ++i) af[i] = *(const bf16x8*)&As[kk][wm * (TM / 2) + i * 16 + l15][quad * 8];
                #pragma unroll
                for (int j = 0; j < 4; ++j) bfr[j] = *(const bf16x8*)&Bs[kk][wn * 64 + j * 16 + l15][quad * 8];
                #pragma unroll
                for (int i = 0; i < MI; ++i)
                    #pragma unroll
                    for (int j = 0; j < 4; ++j)
                        acc[i][j] = __builtin_amdgcn_mfma_f32_16x16x32_bf16(af[i], bfr[j], acc[i][j], 0, 0, 0);
            }
        }
    }
    __syncthreads();
    if constexpr (MODE == 0) {
        float* lsum = (float*)&As[0][0][0];
        lsum[t] = 0.f;
        __syncthreads();
        #pragma unroll
        for (int j = 0; j < 4; ++j) {
            const int cb = wn * 64 + j * 16 + l15;
            const int col = c0 + cb;
            const float b = (float)bias[col];
            float s = 0.f, q = 0.f;
            #pragma unroll
            for (int i = 0; i < MI; ++i) {
                const size_t rbase = (size_t)(row0 + wm * (TM / 2) + i * 16 + quad * 4) * HD + col;
                #pragma unroll
                for (int r = 0; r < 4; ++r) {
                    float y = acc[i][j][r] + b;
                    O[rbase + (size_t)r * HD] = (__bf16)y;
                    s += y;
                    q += y * y;
                }
            }
            s += __shfl_xor(s, 16, 64); s += __shfl_xor(s, 32, 64);
            q += __shfl_xor(q, 16, 64); q += __shfl_xor(q, 32, 64);
            if (quad == 0) {
                atomicAdd(&lsum[cb], s);
                atomicAdd(&lsum[128 + cb], q);
            }
        }
        __syncthreads();
        if (t < 128) atomicAdd(&colsum[c0 + t], lsum[t]);
        else atomicAdd(&colsum[256 + c0 + t - 128], lsum[t]);
    } else {
        float bj[4], wj[4];
        #pragma unroll
        for (int j = 0; j < 4; ++j) {
            const int col = c0 + wn * 64 + j * 16 + l15;
            bj[j] = (float)bias[col];
            wj[j] = (float)W1b[col];
        }
        #pragma unroll
        for (int i = 0; i < MI; ++i) {
            #pragma unroll
            for (int r = 0; r < 4; ++r) {
                float p = 0.f;
                #pragma unroll
                for (int j = 0; j < 4; ++j) p += fmaxf(acc[i][j][r] + bj[j], 0.f) * wj[j];
                p += __shfl_xor(p, 1, 64); p += __shfl_xor(p, 2, 64);
                p += __shfl_xor(p, 4, 64); p += __shfl_xor(p, 8, 64);
                if (l15 == 0) atomicAdd(&x2[row0 + wm * (TM / 2) + i * 16 + quad * 4 + r], p);
            }
        }
    }
}

// ---------------- BN apply, in place: Y (raw bf16) -> relu(BN(Y)) ----------------

__global__ __launch_bounds__(256) void k_bnapply(__bf16* __restrict__ Y, const float* __restrict__ pstat,
                                                 const __bf16* __restrict__ gamma, const __bf16* __restrict__ beta) {
    __shared__ float sc[256], sh[256];
    const int t = threadIdx.x;
    {
        const float invn = 1.0f / NN;
        float m = pstat[t] * invn;
        float var = fmaxf(pstat[256 + t] * invn - m * m, 0.f);
        float rs = rsqrtf(var + 1e-5f);
        float s = (float)gamma[t] * rs;
        sc[t] = s;
        sh[t] = (float)beta[t] - m * s;
    }
    __syncthreads();
    size_t i = ((size_t)blockIdx.x * 256 + t) * 8;
    int c = (int)(i & 255);
    bf16x8 y = *(const bf16x8*)&Y[i];
    bf16x8 o;
    #pragma unroll
    for (int j = 0; j < 8; ++j) o[j] = (__bf16)fmaxf((float)y[j] * sc[c + j] + sh[c + j], 0.f);
    *(bf16x8*)&Y[i] = o;
}

// ---------------- fused tail: +b1b, final BN+relu, mlp2 (one block per batch row) ----------------

__global__ __launch_bounds__(256) void k_mlp2(const float* __restrict__ x2, const __bf16* __restrict__ b1b,
                                              const __bf16* __restrict__ gf, const __bf16* __restrict__ bf_,
                                              const __bf16* __restrict__ W2a, const __bf16* __restrict__ b2a,
                                              const __bf16* __restrict__ W2b, const __bf16* __restrict__ b2b,
                                              const int* __restrict__ flags, void* __restrict__ out) {
    __shared__ float row[HD];
    __shared__ float hbuf[HD];
    __shared__ float part[256];
    const int b = blockIdx.x, t = threadIdx.x;
    const float b1 = (float)b1b[0];
    float s = 0.f, q = 0.f, mine = 0.f;
    #pragma unroll
    for (int r = 0; r < 32; ++r) {
        float v = x2[r * HD + t] + b1;
        s += v; q += v * v;
        if (r == b) mine = v;
    }
    float m = s * (1.0f / 32.0f);
    float var = fmaxf(q * (1.0f / 32.0f) - m * m, 0.f);
    float rs = rsqrtf(var + 1e-5f);
    float sc = (float)gf[t] * rs;
    float sh = (float)bf_[t] - m * sc;
    row[t] = fmaxf(mine * sc + sh, 0.f);
    __syncthreads();
    float acc = (float)b2a[t];
    for (int j = 0; j < HD; ++j) acc += row[j] * (float)W2a[j * HD + t];
    hbuf[t] = fmaxf(acc, 0.f);
    __syncthreads();
    const int k = t & 15, g = t >> 4;
    float p = 0.f;
    #pragma unroll
    for (int jj = 0; jj < 16; ++jj) p += hbuf[g * 16 + jj] * (float)W2b[(g * 16 + jj) * 16 + k];
    part[t] = p;
    __syncthreads();
    if (t < 16) {
        float o = (float)b2b[t];
        #pragma unroll
        for (int g2 = 0; g2 < 16; ++g2) o += part[g2 * 16 + t];
        if (flags[0]) ((__bf16*)out)[b * 16 + t] = (__bf16)o;
        else ((float*)out)[b * 16 + t] = o;
    }
}

// ---------------- launcher ----------------

extern "C" void kernel_launch(void* const* d_in, const int* in_sizes, int n_in,
                              void* d_out, int out_size, void* d_ws, size_t ws_size,
                              hipStream_t stream) {
    const int* ei = (const int*)d_in[4];

    char* ws = (char*)d_ws;
    size_t off_ = 0;
    auto ALLOC = [&](size_t b) { char* p = ws + off_; off_ += (b + 255) & ~(size_t)255; return p; };
    int* flags_ = (int*)ALLOC(8);
    // ---- single contiguous zero region: deg, cursor, colsum, x2, gcur ----
    size_t zbeg = off_;
    int* deg_ = (int*)ALLOC(NN * 4);
    int* cursor_ = (int*)ALLOC(NN * 4);
    float* colsum_ = (float*)ALLOC(4 * 512 * 4);
    float* x2_ = (float*)ALLOC(8192 * 4);
    int* gcur_ = (int*)ALLOC(4);
    size_t zlen = off_ - zbeg;
    // ---------------------------------------------------------------------
    int* offs_ = (int*)ALLOC(NN * 4);
    float* invd_ = (float*)ALLOC(NN * 4);
    int* csr_ = (int*)ALLOC((size_t)NE * 4);
    __bf16* blob_ = (__bf16*)ALLOC((size_t)TOTP * 2);
    __bf16* M_ = (__bf16*)ALLOC((size_t)NN * HD * 2);
    __bf16* Xa_ = (__bf16*)ALLOC((size_t)NN * HD * 2);
    __bf16* Xb_ = (__bf16*)ALLOC((size_t)NN * HD * 2);  // first 8 MB doubles as X0c
    __bf16* X0c_ = Xb_;  // dead before layer-1 GEMM writes Xb

    __bf16* Wl0T = blob_ + 0;
    __bf16* Wr0T = blob_ + 32768;
    __bf16* bb0c = blob_ + 65536;
    __bf16* WlT = blob_ + 65792;
    __bf16* WrT = blob_ + 262400;
    __bf16* bbc = blob_ + 459008;
    __bf16* gammac = blob_ + 459776;
    __bf16* betac = blob_ + 460800;
    __bf16* W1aT = blob_ + 461824;
    __bf16* b1ac = blob_ + 723968;
    __bf16* W1bc = blob_ + 724224;
    __bf16* b1bc = blob_ + 724480;
    __bf16* gfc = blob_ + 724481;
    __bf16* bfc = blob_ + 724737;
    __bf16* W2ac = blob_ + 724993;
    __bf16* b2ac = blob_ + 790529;
    __bf16* W2bc = blob_ + 790785;
    __bf16* b2bc = blob_ + 794881;

    PtrTable pt;
    pt.p[0] = d_in[5];  pt.p[1] = d_in[6];  pt.p[2] = d_in[7];  pt.p[3] = d_in[8];
    pt.p[4] = d_in[9];  pt.p[5] = d_in[10]; pt.p[6] = d_in[11]; pt.p[7] = d_in[12];
    pt.p[8] = d_in[13]; pt.p[9] = d_in[14]; pt.p[10] = d_in[15]; pt.p[11] = d_in[16];
    pt.p[12] = d_in[17]; pt.p[13] = d_in[18]; pt.p[14] = d_in[19]; pt.p[15] = d_in[20];
    pt.p[16] = d_in[21]; pt.p[17] = d_in[22];

    hipMemsetAsync(ws + zbeg, 0, zlen, stream);  // deg + cursor + colsum + x2 + gcur
    k_pre<<<4625, 256, 0, stream>>>((const unsigned*)d_in[0], ei, pt, d_in[0], d_in[1], d_in[2], d_in[3],
                                    flags_, deg_, blob_, X0c_);
    k_alloc<<<NN / 256, 256, 0, stream>>>(deg_, gcur_, offs_, invd_);
    k_fill<<<NE / 256, 256, 0, stream>>>(ei, flags_, offs_, cursor_, csr_);

    // layer 0 (K=128)
    k_agg0<<<NN / 32 * 2, 256, 0, stream>>>(X0c_, csr_, offs_, deg_, invd_, M_);
    k_gemm<0, 128><<<dim3(NN / 128, 2), 256, 0, stream>>>(M_, Wl0T, X0c_, Wr0T, bb0c, 128, Xa_, colsum_,
                                                          nullptr, nullptr);
    k_bnapply<<<NN / 8, 256, 0, stream>>>(Xa_, colsum_, gammac, betac);

    // layers 1..3 (K=256)
    __bf16* Xin = Xa_;
    __bf16* Xo = Xb_;
    for (int l = 0; l < 3; ++l) {
        float* cs = colsum_ + (l + 1) * 512;
        k_agg<<<NN / 32 * 4, 256, 0, stream>>>(Xin, csr_, offs_, deg_, invd_, M_);
        k_gemm<0, 128><<<dim3(NN / 128, 2), 256, 0, stream>>>(M_, WlT + (size_t)l * HD * HD, Xin,
                                                              WrT + (size_t)l * HD * HD, bbc + l * HD, 256, Xo,
                                                              cs, nullptr, nullptr);
        k_bnapply<<<NN / 8, 256, 0, stream>>>(Xo, cs, gammac + (l + 1) * HD, betac + (l + 1) * HD);
        __bf16* tmp = Xin; Xin = Xo; Xo = tmp;
    }
    // Xin = post-BN layer-3 output, flat-viewed as [8192, 1024]

    k_gemm<1, 64><<<dim3(8192 / 64, 2), 256, 0, stream>>>(Xin, W1aT, nullptr, nullptr, b1ac, 1024, nullptr,
                                                          nullptr, W1bc, x2_);
    k_mlp2<<<32, 256, 0, stream>>>(x2_, b1bc, gfc, bfc, W2ac, b2ac, W2bc, b2bc, flags_, d_out);
}

// Round 15
// 418.244 us; speedup vs baseline: 1.0647x; 1.0647x over previous
//
#include <hip/hip_runtime.h>

#define NN 32768
#define NE 524288
#define HD 256
#define TOTP 794897

#define GAS __attribute__((address_space(1)))
#define LAS __attribute__((address_space(3)))

typedef __attribute__((ext_vector_type(8))) __bf16 bf16x8;
typedef __attribute__((ext_vector_type(4))) float f32x4;

__device__ __forceinline__ float ld_any(const void* p, int i, int isbf16) {
    return isbf16 ? (float)((const __bf16*)p)[i] : ((const float*)p)[i];
}

struct PtrTable { const void* p[18]; };

// ---------------- fused preprocessing: detect + cvt_params + cvt_x0 + deg ----------------

__global__ __launch_bounds__(256) void k_pre(const unsigned* __restrict__ xw, const int* __restrict__ ei,
                                             PtrTable pt, const void* __restrict__ p0, const void* __restrict__ p1,
                                             const void* __restrict__ p2, const void* __restrict__ p3,
                                             int* __restrict__ flags, int* __restrict__ deg,
                                             __bf16* __restrict__ blob, __bf16* __restrict__ X0c) {
    __shared__ int fl[2];
    const int t = threadIdx.x;
    if (t < 64) {
        unsigned L = xw[t] & 0xFFFFu;
        int e = (int)((L >> 7) & 0xFF);
        unsigned long long b = __ballot(e >= 90 && e <= 135);
        if (t == 0) fl[0] = (b == ~0ULL) ? 1 : 0;  // 1 => bf16 inputs
    } else if (t < 128) {
        int u = t - 64;
        unsigned long long b = __ballot(ei[2 * u + 1] != 0);
        if (t == 64) fl[1] = (b == 0ULL) ? 1 : 0;  // 1 => int64 edges
    }
    __syncthreads();
    const int f0 = fl[0], f1 = fl[1];
    const int blk = blockIdx.x;
    if (blk == 0 && t < 2) flags[t] = fl[t];
    if (blk < 2048) {
        int i0 = (blk * 256 + t) * 8;
        int n = i0 >> 7, f = i0 & 127;
        const void* src = (f < 32) ? p0 : (f < 64) ? p1 : (f < 96) ? p2 : p3;
        int si = n * 32 + (f & 31);
        bf16x8 o;
        #pragma unroll
        for (int j = 0; j < 8; ++j) o[j] = (__bf16)ld_any(src, si + j, f0);
        *(bf16x8*)&X0c[i0] = o;
    } else if (blk < 3601) {
        const int off[23] = {0, 32768, 65536, 65792, 131328, 196864, 262400, 327936, 393472,
                             459008, 459776, 460800, 461824, 723968, 724224, 724480, 724481,
                             724737, 724993, 790529, 790785, 794881, TOTP};
        const signed char pidx[22] = {0, 1, 2, 3, 3, 3, 4, 4, 4, 5, 6, 7, 8, 9, 10, 11, 12, 13, 14, 15, 16, 17};
        const int sbase[22] = {0, 0, 0, 0, 65536, 131072, 0, 65536, 131072, 0, 0, 0, 0, 0, 0, 0, 0, 0, 0, 0, 0, 0};
        const signed char lR[22] = {7, 7, -1, 8, 8, 8, 8, 8, 8, -1, -1, -1, 10, -1, -1, -1, -1, -1, -1, -1, -1, -1};
        const signed char lC[22] = {8, 8, 0, 8, 8, 8, 8, 8, 8, 0, 0, 0, 8, 0, 0, 0, 0, 0, 0, 0, 0, 0};
        int base = ((blk - 2048) * 256 + t) * 2;
        #pragma unroll
        for (int j = 0; j < 2; ++j) {
            int i = base + j;
            if (i >= TOTP) break;
            int s = 0;
            while (i >= off[s + 1]) ++s;
            int jj = i - off[s];
            int si;
            if (lR[s] >= 0) {
                int Rm = (1 << lR[s]) - 1;
                si = sbase[s] + ((jj & Rm) << lC[s]) + (jj >> lR[s]);  // transpose read
            } else {
                si = sbase[s] + jj;
            }
            blob[i] = (__bf16)ld_any(pt.p[pidx[s]], si, f0);
        }
    } else {
        int e0 = ((blk - 3601) * 256 + t) * 2;
        int d0 = f1 ? ei[2 * e0] : ei[e0];
        int d1 = f1 ? ei[2 * e0 + 2] : ei[e0 + 1];
        atomicAdd(&deg[d0], 1);
        atomicAdd(&deg[d1], 1);
    }
}

// ---------------- CSR region allocation ----------------

__global__ __launch_bounds__(256) void k_alloc(const int* __restrict__ deg, int* __restrict__ gcur,
                                               int* __restrict__ offs, float* __restrict__ invd) {
    const int n = blockIdx.x * 256 + threadIdx.x;
    const int lane = threadIdx.x & 63;
    const int v = deg[n];
    invd[n] = v ? 1.f / (float)v : 0.f;
    int incl = v;
    #pragma unroll
    for (int d = 1; d < 64; d <<= 1) {
        int y = __shfl_up(incl, d, 64);
        if (lane >= d) incl += y;
    }
    int base = 0;
    if (lane == 63) base = atomicAdd(gcur, incl);
    base = __shfl(base, 63, 64);
    offs[n] = base + incl - v;
}

__global__ __launch_bounds__(256) void k_fill(const int* __restrict__ ei, const int* __restrict__ flags,
                                              const int* __restrict__ offs, int* __restrict__ cursor,
                                              int* __restrict__ csr) {
    int e = blockIdx.x * 256 + threadIdx.x;
    int f = flags[1];
    int d = f ? ei[2 * e] : ei[e];
    int s = f ? ei[2 * NE + 2 * e] : ei[NE + e];
    int p = atomicAdd(&cursor[d], 1);
    csr[offs[d] + p] = s;
}

// ---------------- mean aggregation, slice statically bound to XCD ----------------
// blockIdx % nslices = slice; each XCD's 4 MB L2 holds one 64-feat column slice
// (FETCH 105 -> 37 MB, r10). csr/X loads CACHED (NT on csr cost +20us/agg, r10).
// 8-wide fully-unrolled MASKED edge blocks (r12: -22us). 16-wide REGRESSED
// (r14: +24us — 33% slot inflation + 64 extra live VGPRs): 8 is the knee.

__global__ __launch_bounds__(256) void k_agg0(const __bf16* __restrict__ X, const int* __restrict__ csr,
                                              const int* __restrict__ offs, const int* __restrict__ deg,
                                              const float* __restrict__ invd, __bf16* __restrict__ M) {
    const int t = threadIdx.x;
    const int s = blockIdx.x & 1;           // slice (2 x 64 feats, 4 MB each)
    const int n = (blockIdx.x >> 1) * 32 + (t >> 3);
    const int fo = s * 64 + (t & 7) * 8;
    const int beg = offs[n], end = beg + deg[n];
    float a[8] = {};
    for (int e = beg; e < end; e += 8) {
        #pragma unroll
        for (int u = 0; u < 8; ++u) {
            int ee = e + u;
            int idx = csr[ee < end ? ee : end - 1] & (NN - 1);
            float mk = ee < end ? 1.f : 0.f;
            bf16x8 v = *(const bf16x8*)&X[(size_t)idx * 128 + fo];
            #pragma unroll
            for (int j = 0; j < 8; ++j) a[j] += mk * (float)v[j];
        }
    }
    const float id = invd[n];
    bf16x8 o;
    #pragma unroll
    for (int j = 0; j < 8; ++j) o[j] = (__bf16)(a[j] * id);
    *(bf16x8*)&M[(size_t)n * 128 + fo] = o;
}

__global__ __launch_bounds__(256) void k_agg(const __bf16* __restrict__ X, const int* __restrict__ csr,
                                             const int* __restrict__ offs, const int* __restrict__ deg,
                                             const float* __restrict__ invd, __bf16* __restrict__ M) {
    const int t = threadIdx.x;
    const int s = blockIdx.x & 3;           // slice (4 x 64 feats, 4 MB each)
    const int n = (blockIdx.x >> 2) * 32 + (t >> 3);
    const int fo = s * 64 + (t & 7) * 8;
    const int beg = offs[n], end = beg + deg[n];
    float a[8] = {};
    for (int e = beg; e < end; e += 8) {
        #pragma unroll
        for (int u = 0; u < 8; ++u) {
            int ee = e + u;
            int idx = csr[ee < end ? ee : end - 1] & (NN - 1);
            float mk = ee < end ? 1.f : 0.f;
            bf16x8 v = *(const bf16x8*)&X[(size_t)idx * HD + fo];
            #pragma unroll
            for (int j = 0; j < 8; ++j) a[j] += mk * (float)v[j];
        }
    }
    const float id = invd[n];
    bf16x8 o;
    #pragma unroll
    for (int j = 0; j < 8; ++j) o[j] = (__bf16)(a[j] * id);
    *(bf16x8*)&M[(size_t)n * HD + fo] = o;
}

// ---------------- MFMA GEMM, BK=64 ----------------

template <int MODE, int TM>
__global__ __launch_bounds__(256) void k_gemm(const __bf16* __restrict__ A1, const __bf16* __restrict__ WT1,
                                              const __bf16* __restrict__ A2, const __bf16* __restrict__ WT2,
                                              const __bf16* __restrict__ bias, int KD,
                                              __bf16* __restrict__ O, float* __restrict__ colsum,
                                              const __bf16* __restrict__ W1b, float* __restrict__ x2) {
    constexpr int MI = TM / 32;
    __shared__ __bf16 As[2][TM][32];
    __shared__ __bf16 Bs[2][128][32];
    const int t = threadIdx.x;
    const int lane = t & 63, w = t >> 6;
    const int wm = w >> 1, wn = w & 1;
    const int quad = lane >> 4, l15 = lane & 15;
    const int row0 = blockIdx.x * TM, c0 = blockIdx.y * 128;
    const int dr = lane >> 2, dc = (lane & 3) * 8;
    f32x4 acc[MI][4] = {};
    const int npass = A2 ? 2 : 1;
    for (int pass = 0; pass < npass; ++pass) {
        const __bf16* __restrict__ A = pass ? A2 : A1;
        const __bf16* __restrict__ WT = pass ? WT2 : WT1;
        for (int k0 = 0; k0 < KD; k0 += 64) {
            __syncthreads();
            #pragma unroll
            for (int kk = 0; kk < 2; ++kk) {
                #pragma unroll
                for (int i = 0; i < 2; ++i) {
                    const __bf16* g = &WT[(size_t)(c0 + w * 32 + i * 16 + dr) * KD + k0 + kk * 32 + dc];
                    __builtin_amdgcn_global_load_lds((const GAS void*)g, (LAS void*)&Bs[kk][w * 32 + i * 16][0],
                                                     16, 0, 0);
                }
                #pragma unroll
                for (int i = 0; i < TM / 64; ++i) {
                    const __bf16* g = &A[(size_t)(row0 + w * (TM / 4) + i * 16 + dr) * KD + k0 + kk * 32 + dc];
                    __builtin_amdgcn_global_load_lds((const GAS void*)g,
                                                     (LAS void*)&As[kk][w * (TM / 4) + i * 16][0], 16, 0, 0);
                }
            }
            __syncthreads();
            #pragma unroll
            for (int kk = 0; kk < 2; ++kk) {
                bf16x8 af[MI], bfr[4];
                #pragma unroll
                for (int i = 0; i < MI; ++i) af[i] = *(const bf16x8*)&As[kk][wm * (TM / 2) + i * 16 + l15][quad * 8];
                #pragma unroll
                for (int j = 0; j < 4; ++j) bfr[j] = *(const bf16x8*)&Bs[kk][wn * 64 + j * 16 + l15][quad * 8];
                #pragma unroll
                for (int i = 0; i < MI; ++i)
                    #pragma unroll
                    for (int j = 0; j < 4; ++j)
                        acc[i][j] = __builtin_amdgcn_mfma_f32_16x16x32_bf16(af[i], bfr[j], acc[i][j], 0, 0, 0);
            }
        }
    }
    __syncthreads();
    if constexpr (MODE == 0) {
        float* lsum = (float*)&As[0][0][0];
        lsum[t] = 0.f;
        __syncthreads();
        #pragma unroll
        for (int j = 0; j < 4; ++j) {
            const int cb = wn * 64 + j * 16 + l15;
            const int col = c0 + cb;
            const float b = (float)bias[col];
            float s = 0.f, q = 0.f;
            #pragma unroll
            for (int i = 0; i < MI; ++i) {
                const size_t rbase = (size_t)(row0 + wm * (TM / 2) + i * 16 + quad * 4) * HD + col;
                #pragma unroll
                for (int r = 0; r < 4; ++r) {
                    float y = acc[i][j][r] + b;
                    O[rbase + (size_t)r * HD] = (__bf16)y;
                    s += y;
                    q += y * y;
                }
            }
            s += __shfl_xor(s, 16, 64); s += __shfl_xor(s, 32, 64);
            q += __shfl_xor(q, 16, 64); q += __shfl_xor(q, 32, 64);
            if (quad == 0) {
                atomicAdd(&lsum[cb], s);
                atomicAdd(&lsum[128 + cb], q);
            }
        }
        __syncthreads();
        if (t < 128) atomicAdd(&colsum[c0 + t], lsum[t]);
        else atomicAdd(&colsum[256 + c0 + t - 128], lsum[t]);
    } else {
        float bj[4], wj[4];
        #pragma unroll
        for (int j = 0; j < 4; ++j) {
            const int col = c0 + wn * 64 + j * 16 + l15;
            bj[j] = (float)bias[col];
            wj[j] = (float)W1b[col];
        }
        #pragma unroll
        for (int i = 0; i < MI; ++i) {
            #pragma unroll
            for (int r = 0; r < 4; ++r) {
                float p = 0.f;
                #pragma unroll
                for (int j = 0; j < 4; ++j) p += fmaxf(acc[i][j][r] + bj[j], 0.f) * wj[j];
                p += __shfl_xor(p, 1, 64); p += __shfl_xor(p, 2, 64);
                p += __shfl_xor(p, 4, 64); p += __shfl_xor(p, 8, 64);
                if (l15 == 0) atomicAdd(&x2[row0 + wm * (TM / 2) + i * 16 + quad * 4 + r], p);
            }
        }
    }
}

// ---------------- BN apply, in place: Y (raw bf16) -> relu(BN(Y)) ----------------

__global__ __launch_bounds__(256) void k_bnapply(__bf16* __restrict__ Y, const float* __restrict__ pstat,
                                                 const __bf16* __restrict__ gamma, const __bf16* __restrict__ beta) {
    __shared__ float sc[256], sh[256];
    const int t = threadIdx.x;
    {
        const float invn = 1.0f / NN;
        float m = pstat[t] * invn;
        float var = fmaxf(pstat[256 + t] * invn - m * m, 0.f);
        float rs = rsqrtf(var + 1e-5f);
        float s = (float)gamma[t] * rs;
        sc[t] = s;
        sh[t] = (float)beta[t] - m * s;
    }
    __syncthreads();
    size_t i = ((size_t)blockIdx.x * 256 + t) * 8;
    int c = (int)(i & 255);
    bf16x8 y = *(const bf16x8*)&Y[i];
    bf16x8 o;
    #pragma unroll
    for (int j = 0; j < 8; ++j) o[j] = (__bf16)fmaxf((float)y[j] * sc[c + j] + sh[c + j], 0.f);
    *(bf16x8*)&Y[i] = o;
}

// ---------------- fused tail: +b1b, final BN+relu, mlp2 (one block per batch row) ----------------

__global__ __launch_bounds__(256) void k_mlp2(const float* __restrict__ x2, const __bf16* __restrict__ b1b,
                                              const __bf16* __restrict__ gf, const __bf16* __restrict__ bf_,
                                              const __bf16* __restrict__ W2a, const __bf16* __restrict__ b2a,
                                              const __bf16* __restrict__ W2b, const __bf16* __restrict__ b2b,
                                              const int* __restrict__ flags, void* __restrict__ out) {
    __shared__ float row[HD];
    __shared__ float hbuf[HD];
    __shared__ float part[256];
    const int b = blockIdx.x, t = threadIdx.x;
    const float b1 = (float)b1b[0];
    float s = 0.f, q = 0.f, mine = 0.f;
    #pragma unroll
    for (int r = 0; r < 32; ++r) {
        float v = x2[r * HD + t] + b1;
        s += v; q += v * v;
        if (r == b) mine = v;
    }
    float m = s * (1.0f / 32.0f);
    float var = fmaxf(q * (1.0f / 32.0f) - m * m, 0.f);
    float rs = rsqrtf(var + 1e-5f);
    float sc = (float)gf[t] * rs;
    float sh = (float)bf_[t] - m * sc;
    row[t] = fmaxf(mine * sc + sh, 0.f);
    __syncthreads();
    float acc = (float)b2a[t];
    for (int j = 0; j < HD; ++j) acc += row[j] * (float)W2a[j * HD + t];
    hbuf[t] = fmaxf(acc, 0.f);
    __syncthreads();
    const int k = t & 15, g = t >> 4;
    float p = 0.f;
    #pragma unroll
    for (int jj = 0; jj < 16; ++jj) p += hbuf[g * 16 + jj] * (float)W2b[(g * 16 + jj) * 16 + k];
    part[t] = p;
    __syncthreads();
    if (t < 16) {
        float o = (float)b2b[t];
        #pragma unroll
        for (int g2 = 0; g2 < 16; ++g2) o += part[g2 * 16 + t];
        if (flags[0]) ((__bf16*)out)[b * 16 + t] = (__bf16)o;
        else ((float*)out)[b * 16 + t] = o;
    }
}

// ---------------- launcher ----------------

extern "C" void kernel_launch(void* const* d_in, const int* in_sizes, int n_in,
                              void* d_out, int out_size, void* d_ws, size_t ws_size,
                              hipStream_t stream) {
    const int* ei = (const int*)d_in[4];

    char* ws = (char*)d_ws;
    size_t off_ = 0;
    auto ALLOC = [&](size_t b) { char* p = ws + off_; off_ += (b + 255) & ~(size_t)255; return p; };
    int* flags_ = (int*)ALLOC(8);
    // ---- single contiguous zero region: deg, cursor, colsum, x2, gcur ----
    size_t zbeg = off_;
    int* deg_ = (int*)ALLOC(NN * 4);
    int* cursor_ = (int*)ALLOC(NN * 4);
    float* colsum_ = (float*)ALLOC(4 * 512 * 4);
    float* x2_ = (float*)ALLOC(8192 * 4);
    int* gcur_ = (int*)ALLOC(4);
    size_t zlen = off_ - zbeg;
    // ---------------------------------------------------------------------
    int* offs_ = (int*)ALLOC(NN * 4);
    float* invd_ = (float*)ALLOC(NN * 4);
    int* csr_ = (int*)ALLOC((size_t)NE * 4);
    __bf16* blob_ = (__bf16*)ALLOC((size_t)TOTP * 2);
    __bf16* M_ = (__bf16*)ALLOC((size_t)NN * HD * 2);
    __bf16* Xa_ = (__bf16*)ALLOC((size_t)NN * HD * 2);
    __bf16* Xb_ = (__bf16*)ALLOC((size_t)NN * HD * 2);  // first 8 MB doubles as X0c
    __bf16* X0c_ = Xb_;  // dead before layer-1 GEMM writes Xb

    __bf16* Wl0T = blob_ + 0;
    __bf16* Wr0T = blob_ + 32768;
    __bf16* bb0c = blob_ + 65536;
    __bf16* WlT = blob_ + 65792;
    __bf16* WrT = blob_ + 262400;
    __bf16* bbc = blob_ + 459008;
    __bf16* gammac = blob_ + 459776;
    __bf16* betac = blob_ + 460800;
    __bf16* W1aT = blob_ + 461824;
    __bf16* b1ac = blob_ + 723968;
    __bf16* W1bc = blob_ + 724224;
    __bf16* b1bc = blob_ + 724480;
    __bf16* gfc = blob_ + 724481;
    __bf16* bfc = blob_ + 724737;
    __bf16* W2ac = blob_ + 724993;
    __bf16* b2ac = blob_ + 790529;
    __bf16* W2bc = blob_ + 790785;
    __bf16* b2bc = blob_ + 794881;

    PtrTable pt;
    pt.p[0] = d_in[5];  pt.p[1] = d_in[6];  pt.p[2] = d_in[7];  pt.p[3] = d_in[8];
    pt.p[4] = d_in[9];  pt.p[5] = d_in[10]; pt.p[6] = d_in[11]; pt.p[7] = d_in[12];
    pt.p[8] = d_in[13]; pt.p[9] = d_in[14]; pt.p[10] = d_in[15]; pt.p[11] = d_in[16];
    pt.p[12] = d_in[17]; pt.p[13] = d_in[18]; pt.p[14] = d_in[19]; pt.p[15] = d_in[20];
    pt.p[16] = d_in[21]; pt.p[17] = d_in[22];

    hipMemsetAsync(ws + zbeg, 0, zlen, stream);  // deg + cursor + colsum + x2 + gcur
    k_pre<<<4625, 256, 0, stream>>>((const unsigned*)d_in[0], ei, pt, d_in[0], d_in[1], d_in[2], d_in[3],
                                    flags_, deg_, blob_, X0c_);
    k_alloc<<<NN / 256, 256, 0, stream>>>(deg_, gcur_, offs_, invd_);
    k_fill<<<NE / 256, 256, 0, stream>>>(ei, flags_, offs_, cursor_, csr_);

    // layer 0 (K=128)
    k_agg0<<<NN / 32 * 2, 256, 0, stream>>>(X0c_, csr_, offs_, deg_, invd_, M_);
    k_gemm<0, 128><<<dim3(NN / 128, 2), 256, 0, stream>>>(M_, Wl0T, X0c_, Wr0T, bb0c, 128, Xa_, colsum_,
                                                          nullptr, nullptr);
    k_bnapply<<<NN / 8, 256, 0, stream>>>(Xa_, colsum_, gammac, betac);

    // layers 1..3 (K=256)
    __bf16* Xin = Xa_;
    __bf16* Xo = Xb_;
    for (int l = 0; l < 3; ++l) {
        float* cs = colsum_ + (l + 1) * 512;
        k_agg<<<NN / 32 * 4, 256, 0, stream>>>(Xin, csr_, offs_, deg_, invd_, M_);
        k_gemm<0, 128><<<dim3(NN / 128, 2), 256, 0, stream>>>(M_, WlT + (size_t)l * HD * HD, Xin,
                                                              WrT + (size_t)l * HD * HD, bbc + l * HD, 256, Xo,
                                                              cs, nullptr, nullptr);
        k_bnapply<<<NN / 8, 256, 0, stream>>>(Xo, cs, gammac + (l + 1) * HD, betac + (l + 1) * HD);
        __bf16* tmp = Xin; Xin = Xo; Xo = tmp;
    }
    // Xin = post-BN layer-3 output, flat-viewed as [8192, 1024]

    k_gemm<1, 64><<<dim3(8192 / 64, 2), 256, 0, stream>>>(Xin, W1aT, nullptr, nullptr, b1ac, 1024, nullptr,
                                                          nullptr, W1bc, x2_);
    k_mlp2<<<32, 256, 0, stream>>>(x2_, b1bc, gfc, bfc, W2ac, b2ac, W2bc, b2bc, flags_, d_out);
}